// Round 3
// baseline (1607.016 us; speedup 1.0000x reference)
//
#include <hip/hip_runtime.h>
#include <hip/hip_bf16.h>

// 2-layer tanh RNN. B=256, T=1024, H=128, V=96. x int32; float tensors fp32
// (per reference) — but we runtime-detect fp32 vs bf16 to be robust.
// d_in: 0:x 1:emb 2:W_ih0 3:W_hh0 4:b_ih0 5:b_hh0 6:W_ih1 7:W_hh1 8:b_ih1
//       9:b_hh1 10:fc_W 11:fc_b
// d_out: out[B*T,96] (25165824) ++ hidden[2,B,128] (65536), same dtype as inputs.

#define B_SZ 256
#define T_LEN 1024
#define HD 128
#define VC 96
#define OUT_MAIN (B_SZ * T_LEN * VC)
#define HID_OFF OUT_MAIN

__device__ __forceinline__ float bf2f(__hip_bfloat16 v) { return __bfloat162float(v); }

// Runtime dtype probe: true bf16 data here is all |v|<0.5 → bf16-exp<127 for
// every 16-bit word. fp32 data's low halves are random mantissa bits → ~50%
// have bf16-exp>=127. Read first 128 ushorts of emb (256 B, safe either way).
__device__ __forceinline__ bool detect_f32(const void* emb) {
  const unsigned short* u = (const unsigned short*)emb;
  int hits = 0;
#pragma unroll
  for (int i = 0; i < 128; ++i) {
    hits += (((u[i] >> 7) & 0xFF) >= 127);
  }
  return hits > 2;
}

__device__ __forceinline__ float ldw(const void* p, int i, bool f32) {
  return f32 ? ((const float*)p)[i] : bf2f(((const __hip_bfloat16*)p)[i]);
}

__device__ __forceinline__ float tanh_fast(float x) {
  float ax = fabsf(x);
  float e = __expf(-2.0f * ax);
  float y = 1.0f - 2.0f * __fdividef(e, 1.0f + e);
  return copysignf(y, x);
}

// embp[v][r] = sum_j W_ih0[r][j]*emb[v][j] + b_ih0[r] + b_hh0[r]   (ws path)
__global__ __launch_bounds__(128) void embp_kernel(
    const void* __restrict__ emb, const void* __restrict__ Wih0,
    const void* __restrict__ bih0, const void* __restrict__ bhh0,
    float* __restrict__ embp) {
  const bool f32 = detect_f32(emb);
  __shared__ float ev[HD];
  const int v = blockIdx.x, r = threadIdx.x;
  ev[r] = ldw(emb, v * HD + r, f32);
  __syncthreads();
  float acc = ldw(bih0, r, f32) + ldw(bhh0, r, f32);
#pragma unroll 8
  for (int j = 0; j < HD; ++j) acc += ldw(Wih0, r * HD + j, f32) * ev[j];
  embp[v * HD + r] = acc;
}

// One block = one batch sequence. 512 threads = 8 waves.
// Per step: P1 (Whh0 h0 + Whh1 h1) |B1| P2 (Wih1 h0', h1 update) |B2| P3 (FC) |B3|
template <bool USE_WS>
__global__ __launch_bounds__(512, 2) void rnn_fused(
    const int* __restrict__ x,
    const float* __restrict__ embp_g,   // valid iff USE_WS
    const void* __restrict__ emb,
    const void* __restrict__ Wih0,
    const void* __restrict__ bih0,
    const void* __restrict__ bhh0,
    const void* __restrict__ Whh0,
    const void* __restrict__ Wih1,
    const void* __restrict__ Whh1,
    const void* __restrict__ bih1,
    const void* __restrict__ bhh1,
    const void* __restrict__ fcW,
    const void* __restrict__ fcb_g,
    void* __restrict__ out) {
  __shared__ __align__(16) float embp[VC * HD];   // 48 KB
  __shared__ __align__(16) float h0[2][HD];
  __shared__ __align__(16) float h1[2][HD];
  __shared__ __align__(16) float r1buf[HD];
  __shared__ __align__(16) float xb1[HD];
  __shared__ __align__(16) float fcb[VC];
  __shared__ __align__(16) int xrow[T_LEN];       // 4 KB

  const int tid = threadIdx.x;
  const int b = blockIdx.x;
  const bool f32 = detect_f32(emb);

  // ---- init staging ----
  xrow[tid] = x[b * T_LEN + tid];
  xrow[tid + 512] = x[b * T_LEN + 512 + tid];

  if constexpr (USE_WS) {
    const float4* src = (const float4*)embp_g;
    float4* dst = (float4*)embp;
#pragma unroll
    for (int i = 0; i < (VC * HD / 4) / 512; ++i) dst[tid + i * 512] = src[tid + i * 512];
  } else {
    // In-kernel embp fallback: thread (r, vg) handles 24 vocab rows.
    const int r = tid & 127, vg = tid >> 7;
    const float bsum = ldw(bih0, r, f32) + ldw(bhh0, r, f32);
    for (int vi = 0; vi < 24; ++vi) {
      const int v = vg * 24 + vi;
      float acc = bsum;
#pragma unroll 8
      for (int k = 0; k < HD; ++k)
        acc += ldw(Wih0, r * HD + k, f32) * ldw(emb, v * HD + k, f32);
      embp[v * HD + r] = acc;
    }
  }

  if (tid < HD) {
    xb1[tid] = ldw(bih1, tid, f32) + ldw(bhh1, tid, f32);
    h0[0][tid] = 0.f; h0[1][tid] = 0.f; h1[0][tid] = 0.f; h1[1][tid] = 0.f;
  }
  if (tid < VC) fcb[tid] = ldw(fcb_g, tid, f32);

  // ---- weight registers ----
  // P1: two matvecs (m=0: Whh0, m=1: Whh1), row r1i, K-half half1
  const int m1 = tid >> 8;
  const int r1i = (tid >> 1) & 127;
  const int half1 = tid & 1;
  float w1[64];
  {
    const void* wsrc = m1 ? Whh1 : Whh0;
    const int base = r1i * HD + half1 * 64;
#pragma unroll
    for (int j = 0; j < 64; ++j) w1[j] = ldw(wsrc, base + j, f32);
  }
  // P2: Wih1 matvec, row r2i, K quarter q2
  const int r2i = tid >> 2;
  const int q2 = tid & 3;
  float w2[32];
  {
    const int base = r2i * HD + q2 * 32;
#pragma unroll
    for (int j = 0; j < 32; ++j) w2[j] = ldw(Wih1, base + j, f32);
  }
  // P3: FC, row v3 (<96); threads >= 384 idle in P3
  const bool p3act = (tid < VC * 4);
  const int v3 = p3act ? (tid >> 2) : 0;
  float w3[32];
  {
    const int base = v3 * HD + q2 * 32;
#pragma unroll
    for (int j = 0; j < 32; ++j) w3[j] = ldw(fcW, base + j, f32);
  }
  __syncthreads();

  float* outf = (float*)out;
  __hip_bfloat16* outb = (__hip_bfloat16*)out;
  const long out_row_base = (long)b * T_LEN;

  for (int t = 0; t < T_LEN; ++t) {
    const int rd = t & 1, wr = rd ^ 1;

    // ---- P1: s = (m1 ? Whh1 h1 : Whh0 h0), K-split 2 ----
    {
      const float* hsrc = (m1 ? h1[rd] : h0[rd]) + half1 * 64;
      float a0 = 0.f, a1 = 0.f, a2 = 0.f, a3 = 0.f;
#pragma unroll
      for (int j = 0; j < 64; j += 4) {
        const float4 h4 = *(const float4*)(hsrc + j);
        a0 += w1[j + 0] * h4.x; a1 += w1[j + 1] * h4.y;
        a2 += w1[j + 2] * h4.z; a3 += w1[j + 3] * h4.w;
      }
      float s = (a0 + a1) + (a2 + a3);
      s += __shfl_xor(s, 1);
      if (m1 == 0) {
        const int xt = xrow[t];
        const float hv = tanh_fast(embp[xt * HD + r1i] + s);
        if (!half1) h0[wr][r1i] = hv;
      } else {
        if (!half1) r1buf[r1i] = s;
      }
    }
    __syncthreads();  // B1

    // ---- P2: h1' = tanh(xb1 + r1 + Wih1 h0'), K-split 4 ----
    {
      const float* h0n = h0[wr] + q2 * 32;
      float c0 = 0.f, c1 = 0.f, c2 = 0.f, c3 = 0.f;
#pragma unroll
      for (int j = 0; j < 32; j += 4) {
        const float4 h4 = *(const float4*)(h0n + j);
        c0 += w2[j + 0] * h4.x; c1 += w2[j + 1] * h4.y;
        c2 += w2[j + 2] * h4.z; c3 += w2[j + 3] * h4.w;
      }
      float s2 = (c0 + c1) + (c2 + c3);
      s2 += __shfl_xor(s2, 1);
      s2 += __shfl_xor(s2, 2);
      if (q2 == 0) h1[wr][r2i] = tanh_fast(xb1[r2i] + r1buf[r2i] + s2);
    }
    __syncthreads();  // B2

    // ---- P3: out_t = fcW h1' + fcb, K-split 4 ----
    if (p3act) {
      const float* h1n = h1[wr] + q2 * 32;
      float c0 = 0.f, c1 = 0.f, c2 = 0.f, c3 = 0.f;
#pragma unroll
      for (int j = 0; j < 32; j += 4) {
        const float4 h4 = *(const float4*)(h1n + j);
        c0 += w3[j + 0] * h4.x; c1 += w3[j + 1] * h4.y;
        c2 += w3[j + 2] * h4.z; c3 += w3[j + 3] * h4.w;
      }
      float s3 = (c0 + c1) + (c2 + c3);
      s3 += __shfl_xor(s3, 1);
      s3 += __shfl_xor(s3, 2);
      if (q2 == 0) {
        const float val = s3 + fcb[v3];
        const long idx = (out_row_base + t) * VC + v3;
        if (f32) outf[idx] = val; else outb[idx] = __float2bfloat16(val);
      }
    }
    __syncthreads();  // B3 (defensive; removal candidate once green)
  }

  // final hidden: t=1023 => wr==0
  if (tid < HD) {
    const long idx = HID_OFF + (long)b * HD + tid;
    if (f32) outf[idx] = h0[0][tid]; else outb[idx] = __float2bfloat16(h0[0][tid]);
  } else if (tid < 2 * HD) {
    const int r = tid - HD;
    const long idx = HID_OFF + (long)B_SZ * HD + (long)b * HD + r;
    if (f32) outf[idx] = h1[0][r]; else outb[idx] = __float2bfloat16(h1[0][r]);
  }
}

extern "C" void kernel_launch(void* const* d_in, const int* in_sizes, int n_in,
                              void* d_out, int out_size, void* d_ws, size_t ws_size,
                              hipStream_t stream) {
  const int* x = (const int*)d_in[0];
  const void* emb = d_in[1];
  const void* Wih0 = d_in[2];
  const void* Whh0 = d_in[3];
  const void* bih0 = d_in[4];
  const void* bhh0 = d_in[5];
  const void* Wih1 = d_in[6];
  const void* Whh1 = d_in[7];
  const void* bih1 = d_in[8];
  const void* bhh1 = d_in[9];
  const void* fcW = d_in[10];
  const void* fcb = d_in[11];

  const size_t need = (size_t)VC * HD * sizeof(float);  // 48 KB
  if (d_ws != nullptr && ws_size >= need) {
    float* embp = (float*)d_ws;
    embp_kernel<<<VC, HD, 0, stream>>>(emb, Wih0, bih0, bhh0, embp);
    rnn_fused<true><<<B_SZ, 512, 0, stream>>>(x, embp, emb, Wih0, bih0, bhh0,
                                              Whh0, Wih1, Whh1, bih1, bhh1,
                                              fcW, fcb, d_out);
  } else {
    rnn_fused<false><<<B_SZ, 512, 0, stream>>>(x, nullptr, emb, Wih0, bih0, bhh0,
                                               Whh0, Wih1, Whh1, bih1, bhh1,
                                               fcW, fcb, d_out);
  }
}

// Round 4
// 1269.835 us; speedup vs baseline: 1.2655x; 1.2655x over previous
//
#include <hip/hip_runtime.h>
#include <hip/hip_bf16.h>

// 2-layer tanh RNN. B=256, T=1024, H=128, V=96. x int32; float tensors
// runtime-detected fp32 vs bf16 (r3: detection path passed).
// d_in: 0:x 1:emb 2:W_ih0 3:W_hh0 4:b_ih0 5:b_hh0 6:W_ih1 7:W_hh1 8:b_ih1
//       9:b_hh1 10:fc_W 11:fc_b
// d_out: out[B*T,96] ++ hidden[2,B,128]

#define B_SZ 256
#define T_LEN 1024
#define HD 128
#define VC 96
#define OUT_MAIN (B_SZ * T_LEN * VC)
#define HID_OFF OUT_MAIN

// padded h layout: chunk c (16 floats) at float-offset 20c → chunk starts hit
// banks {0,20,8,28,16,4,24,12} → conflict-free K-sliced b128 reads.
#define HPAD(k) ((k) + 4 * ((k) >> 4))
#define HP_SZ 160

__device__ __forceinline__ float bf2f(__hip_bfloat16 v) { return __bfloat162float(v); }

__device__ __forceinline__ bool detect_f32(const void* emb) {
  const unsigned short* u = (const unsigned short*)emb;
  int hits = 0;
#pragma unroll
  for (int i = 0; i < 128; ++i) hits += (((u[i] >> 7) & 0xFF) >= 127);
  return hits > 2;
}

__device__ __forceinline__ float ldw(const void* p, int i, bool f32) {
  return f32 ? ((const float*)p)[i] : bf2f(((const __hip_bfloat16*)p)[i]);
}

__device__ __forceinline__ float tanh_fast(float x) {
  float ax = fabsf(x);
  float e = __expf(-2.0f * ax);
  float y = 1.0f - 2.0f * __fdividef(e, 1.0f + e);
  return copysignf(y, x);
}

__global__ __launch_bounds__(128) void embp_kernel(
    const void* __restrict__ emb, const void* __restrict__ Wih0,
    const void* __restrict__ bih0, const void* __restrict__ bhh0,
    float* __restrict__ embp) {
  const bool f32 = detect_f32(emb);
  __shared__ float ev[HD];
  const int v = blockIdx.x, r = threadIdx.x;
  ev[r] = ldw(emb, v * HD + r, f32);
  __syncthreads();
  float acc = ldw(bih0, r, f32) + ldw(bhh0, r, f32);
#pragma unroll 8
  for (int j = 0; j < HD; ++j) acc += ldw(Wih0, r * HD + j, f32) * ev[j];
  embp[v * HD + r] = acc;
}

// One block = one batch sequence. 512 threads = 8 waves (2/SIMD).
// Slicing: s = tid&7 owns K-chunk [16s,16s+16) in EVERY phase → h-values read
// in P2 (h0') / P3 (h1') are register-carried into next step's P1 (zero P1 reads).
// Per step: P1 (Whh0·h0 + Whh1·h1, from carried regs) |B1| P2 (Wih1·h0') |B2| P3 (FC).
template <bool USE_WS>
__global__ __launch_bounds__(512, 2) void rnn_fused(
    const int* __restrict__ x,
    const float* __restrict__ embp_g,
    const void* __restrict__ emb,
    const void* __restrict__ Wih0,
    const void* __restrict__ bih0,
    const void* __restrict__ bhh0,
    const void* __restrict__ Whh0,
    const void* __restrict__ Wih1,
    const void* __restrict__ Whh1,
    const void* __restrict__ bih1,
    const void* __restrict__ bhh1,
    const void* __restrict__ fcW,
    const void* __restrict__ fcb_g,
    void* __restrict__ out) {
  __shared__ __align__(16) float embp[VC * HD];   // 48 KB
  __shared__ __align__(16) float h0p[HP_SZ];
  __shared__ __align__(16) float h1p[HP_SZ];
  __shared__ __align__(16) float r1buf[HD];
  __shared__ __align__(16) float xb1[HD];
  __shared__ __align__(16) float fcb[VC];
  __shared__ __align__(16) int xrow[T_LEN];

  const int tid = threadIdx.x;
  const int b = blockIdx.x;
  const bool f32 = detect_f32(emb);

  // ---- init staging ----
  xrow[tid] = x[b * T_LEN + tid];
  xrow[tid + 512] = x[b * T_LEN + 512 + tid];

  if constexpr (USE_WS) {
    const float4* src = (const float4*)embp_g;
    float4* dst = (float4*)embp;
#pragma unroll
    for (int i = 0; i < (VC * HD / 4) / 512; ++i) dst[tid + i * 512] = src[tid + i * 512];
  } else {
    const int r = tid & 127, vg = tid >> 7;
    const float bsum = ldw(bih0, r, f32) + ldw(bhh0, r, f32);
    for (int vi = 0; vi < 24; ++vi) {
      const int v = vg * 24 + vi;
      float acc = bsum;
#pragma unroll 8
      for (int k = 0; k < HD; ++k)
        acc += ldw(Wih0, r * HD + k, f32) * ldw(emb, v * HD + k, f32);
      embp[v * HD + r] = acc;
    }
  }

  if (tid < HD) xb1[tid] = ldw(bih1, tid, f32) + ldw(bhh1, tid, f32);
  if (tid < VC) fcb[tid] = ldw(fcb_g, tid, f32);

  // ---- thread roles ----
  const int s = tid & 7;          // K-chunk (16 floats), consistent across phases
  const int m1 = tid >> 8;        // P1: 0 = layer0 (Whh0), 1 = layer1 (Whh1)
  const int g = (tid >> 3) & 31;  // P1: rows 4g..4g+3
  const int G = tid >> 3;         // P2: rows 2G, 2G+1 (G<64)
  const bool p3act = (tid < VC * 4);  // P3: rows 2G, 2G+1 (G<48)

  // ---- weights in registers ----
  float w1[64];  // P1: 4 rows x 16 cols
  {
    const void* W = m1 ? Whh1 : Whh0;
#pragma unroll
    for (int r = 0; r < 4; ++r)
#pragma unroll
      for (int j = 0; j < 16; ++j)
        w1[r * 16 + j] = ldw(W, (4 * g + r) * HD + 16 * s + j, f32);
  }
  float w2[32];  // P2: 2 rows x 16
#pragma unroll
  for (int r = 0; r < 2; ++r)
#pragma unroll
    for (int j = 0; j < 16; ++j)
      w2[r * 16 + j] = ldw(Wih1, (2 * G + r) * HD + 16 * s + j, f32);
  float w3[32];  // P3: 2 rows x 16
  if (p3act) {
#pragma unroll
    for (int r = 0; r < 2; ++r)
#pragma unroll
      for (int j = 0; j < 16; ++j)
        w3[r * 16 + j] = ldw(fcW, (2 * G + r) * HD + 16 * s + j, f32);
  }

  // carried h-slices (chunk s of h0 / h1), zero-init (h_0 = 0)
  float hc0[16], hc1[16];
#pragma unroll
  for (int j = 0; j < 16; ++j) { hc0[j] = 0.f; hc1[j] = 0.f; }

  __syncthreads();

  float* outf = (float*)out;
  __hip_bfloat16* outb = (__hip_bfloat16*)out;
  const long out_row_base = (long)b * T_LEN;
  const int s1b = s & 1, s2b = (s >> 1) & 1;
  const int permrow = ((s & 1) << 1) | ((s >> 1) & 1);  // {0,2,1,3} for s<4

  for (int t = 0; t < T_LEN; ++t) {
    // ---- P1: rows 4g..4g+3 of (m1? Whh1·h1 : Whh0·h0) from carried regs ----
    float p0 = 0.f, p1 = 0.f, p2 = 0.f, p3 = 0.f;
    if (m1 == 0) {
#pragma unroll
      for (int j = 0; j < 16; ++j) {
        const float hv = hc0[j];
        p0 += w1[j] * hv; p1 += w1[16 + j] * hv;
        p2 += w1[32 + j] * hv; p3 += w1[48 + j] * hv;
      }
    } else {
#pragma unroll
      for (int j = 0; j < 16; ++j) {
        const float hv = hc1[j];
        p0 += w1[j] * hv; p1 += w1[16 + j] * hv;
        p2 += w1[32 + j] * hv; p3 += w1[48 + j] * hv;
      }
    }
    // reduce-scatter over 8 subs: lane s<4 ends with full sum of row 4g+permrow
    {
      const float t0 = __shfl_xor(s1b ? p0 : p2, 1);
      const float t1 = __shfl_xor(s1b ? p1 : p3, 1);
      const float a = (s1b ? p2 : p0) + t0;
      const float bb = (s1b ? p3 : p1) + t1;
      const float u = __shfl_xor(s2b ? a : bb, 2);
      float c = (s2b ? bb : a) + u;
      c += __shfl_xor(c, 4);
      if (s < 4) {
        const int row = 4 * g + permrow;
        if (m1 == 0) {
          const int xt = xrow[t];
          h0p[HPAD(row)] = tanh_fast(embp[xt * HD + row] + c);
        } else {
          r1buf[row] = c;
        }
      }
    }
    __syncthreads();  // B1: h0', r1 visible

    // ---- P2: read h0' chunk s (carry into hc0); rows 2G,2G+1 of Wih1·h0' ----
    {
      const float4* hp = (const float4*)(h0p + 20 * s);
#pragma unroll
      for (int i = 0; i < 4; ++i) {
        const float4 v = hp[i];
        hc0[4 * i + 0] = v.x; hc0[4 * i + 1] = v.y;
        hc0[4 * i + 2] = v.z; hc0[4 * i + 3] = v.w;
      }
      float pA = 0.f, pB = 0.f;
#pragma unroll
      for (int j = 0; j < 16; ++j) {
        const float hv = hc0[j];
        pA += w2[j] * hv; pB += w2[16 + j] * hv;
      }
      const float tt = __shfl_xor(s1b ? pA : pB, 1);
      float p = (s1b ? pB : pA) + tt;   // row 2G + (s&1)
      p += __shfl_xor(p, 2);
      p += __shfl_xor(p, 4);
      if (s < 2) {
        const int row = 2 * G + s;
        h1p[HPAD(row)] = tanh_fast(xb1[row] + r1buf[row] + p);
      }
    }
    __syncthreads();  // B2: h1' visible

    // ---- P3: read h1' chunk s (carry into hc1); FC rows 2G,2G+1 ----
    {
      const float4* hp = (const float4*)(h1p + 20 * s);
#pragma unroll
      for (int i = 0; i < 4; ++i) {
        const float4 v = hp[i];
        hc1[4 * i + 0] = v.x; hc1[4 * i + 1] = v.y;
        hc1[4 * i + 2] = v.z; hc1[4 * i + 3] = v.w;
      }
      if (p3act) {
        float pA = 0.f, pB = 0.f;
#pragma unroll
        for (int j = 0; j < 16; ++j) {
          const float hv = hc1[j];
          pA += w3[j] * hv; pB += w3[16 + j] * hv;
        }
        const float tt = __shfl_xor(s1b ? pA : pB, 1);
        float p = (s1b ? pB : pA) + tt;  // row 2G + (s&1)
        p += __shfl_xor(p, 2);
        p += __shfl_xor(p, 4);
        if (s < 2) {
          const int v3 = 2 * G + s;
          const float val = p + fcb[v3];
          const long idx = (out_row_base + t) * VC + v3;
          if (f32) outf[idx] = val; else outb[idx] = __float2bfloat16(val);
        }
      }
    }
    // no barrier: P1@t+1 writes (h0p, r1buf) are post-B2@t (readers of step t
    // finished pre-B2); P2@t+1's h1p writes are post-B1@t+1 (> all P3@t reads).
  }

  // final hidden (all writes barrier-covered by B1/B2 of t=1023)
  if (tid < HD) {
    const long idx = HID_OFF + (long)b * HD + tid;
    const float v = h0p[HPAD(tid)];
    if (f32) outf[idx] = v; else outb[idx] = __float2bfloat16(v);
  } else if (tid < 2 * HD) {
    const int r = tid - HD;
    const long idx = HID_OFF + (long)B_SZ * HD + (long)b * HD + r;
    const float v = h1p[HPAD(r)];
    if (f32) outf[idx] = v; else outb[idx] = __float2bfloat16(v);
  }
}

extern "C" void kernel_launch(void* const* d_in, const int* in_sizes, int n_in,
                              void* d_out, int out_size, void* d_ws, size_t ws_size,
                              hipStream_t stream) {
  const int* x = (const int*)d_in[0];
  const void* emb = d_in[1];
  const void* Wih0 = d_in[2];
  const void* Whh0 = d_in[3];
  const void* bih0 = d_in[4];
  const void* bhh0 = d_in[5];
  const void* Wih1 = d_in[6];
  const void* Whh1 = d_in[7];
  const void* bih1 = d_in[8];
  const void* bhh1 = d_in[9];
  const void* fcW = d_in[10];
  const void* fcb = d_in[11];

  const size_t need = (size_t)VC * HD * sizeof(float);
  if (d_ws != nullptr && ws_size >= need) {
    float* embp = (float*)d_ws;
    embp_kernel<<<VC, HD, 0, stream>>>(emb, Wih0, bih0, bhh0, embp);
    rnn_fused<true><<<B_SZ, 512, 0, stream>>>(x, embp, emb, Wih0, bih0, bhh0,
                                              Whh0, Wih1, Whh1, bih1, bhh1,
                                              fcW, fcb, d_out);
  } else {
    rnn_fused<false><<<B_SZ, 512, 0, stream>>>(x, nullptr, emb, Wih0, bih0, bhh0,
                                               Whh0, Wih1, Whh1, bih1, bhh1,
                                               fcW, fcb, d_out);
  }
}